// Round 3
// baseline (2828.818 us; speedup 1.0000x reference)
//
#include <hip/hip_runtime.h>
#include <hip/hip_bf16.h>
#include <cstdint>

typedef __hip_bfloat16 bf16;
typedef __attribute__((ext_vector_type(8))) short short8;   // 8 bf16 = 4 VGPRs
typedef __attribute__((ext_vector_type(4))) float f32x4;

__device__ __forceinline__ f32x4 mfma16(short8 a, short8 b, f32x4 c) {
  return __builtin_amdgcn_mfma_f32_16x16x32_bf16(a, b, c, 0, 0, 0);
}

// async global->LDS, 16B/lane; LDS dest = wave-uniform base + lane*16
__device__ __forceinline__ void gload16(const bf16* g, bf16* l) {
  __builtin_amdgcn_global_load_lds((const __attribute__((address_space(1))) void*)g,
                                   (__attribute__((address_space(3))) void*)l, 16, 0, 0);
}

// ---------------- elementwise ----------------

__global__ void __launch_bounds__(256) cvt_f32_bf16(const float* __restrict__ in,
                                                    bf16* __restrict__ out, int n) {
  int i = blockIdx.x * 256 + threadIdx.x;
  if (i < n) out[i] = __float2bfloat16(in[i]);
}

__global__ void __launch_bounds__(256) bcast_latents(const float* __restrict__ lin,
                                                     float* __restrict__ lat) {
  int i = blockIdx.x * 256 + threadIdx.x;
  lat[i] = lin[i & 65535];   // (64,1024) broadcast over 32 batches
}

// ---------------- transposes: K x N f32 -> N x K bf16, optional row-scale ----------------
// scale[k] multiplies W[k][n] (LN-gamma fold).

__device__ __forceinline__ void trans_tile(float (*tile)[33], const float* __restrict__ src,
                                           bf16* __restrict__ dst, const float* __restrict__ scale,
                                           int K, int N, int bx, int by) {
  int n0 = bx * 32, k0 = by * 32;
  int tx = threadIdx.x & 31, ty = threadIdx.x >> 5;
#pragma unroll
  for (int j = 0; j < 32; j += 8)
    tile[ty + j][tx] = src[(size_t)(k0 + ty + j) * N + n0 + tx];
  float sc = scale ? scale[k0 + tx] : 1.f;
  __syncthreads();
#pragma unroll
  for (int j = 0; j < 32; j += 8)
    dst[(size_t)(n0 + ty + j) * K + k0 + tx] = __float2bfloat16(tile[tx][ty + j] * sc);
}

__global__ void __launch_bounds__(256) transpose_cvt(const float* __restrict__ src,
                                                     bf16* __restrict__ dst, int K, int N) {
  __shared__ float tile[32][33];
  trans_tile(tile, src, dst, nullptr, K, N, blockIdx.x, blockIdx.y);
}

// per-layer: wql_t = [g2*Wq | g2*Wkv]^T (3072x1024), wkvx_t = (g1*Wkv)^T,
// wo_t, w1_t = (ffg*W1)^T, w2_t. 14336 tiles.
__global__ void __launch_bounds__(256) transpose_all(
    const float* __restrict__ wq, const float* __restrict__ wkv,
    const float* __restrict__ wo, const float* __restrict__ w1,
    const float* __restrict__ w2, const float* __restrict__ g1,
    const float* __restrict__ g2, const float* __restrict__ ffg,
    bf16* __restrict__ wql_t, bf16* __restrict__ wkvx_t,
    bf16* __restrict__ wo_t, bf16* __restrict__ w1_t, bf16* __restrict__ w2_t) {
  __shared__ float tile[32][33];
  int id = blockIdx.x;
  if (id < 1024) {                       // Wq (1024x1024) -> wql rows 0..1023, scale g2
    trans_tile(tile, wq, wql_t, g2, 1024, 1024, id & 31, id >> 5);
  } else if (id < 3072) {                // Wkv (1024x2048) -> wql rows 1024..3071, scale g2
    id -= 1024;
    trans_tile(tile, wkv, wql_t + (size_t)1024 * 1024, g2, 1024, 2048, id & 63, id >> 6);
  } else if (id < 5120) {                // Wkv -> wkvx, scale g1
    id -= 3072;
    trans_tile(tile, wkv, wkvx_t, g1, 1024, 2048, id & 63, id >> 6);
  } else if (id < 6144) {                // Wo
    id -= 5120;
    trans_tile(tile, wo, wo_t, nullptr, 1024, 1024, id & 31, id >> 5);
  } else if (id < 10240) {               // W1 (1024x4096), scale ffg
    id -= 6144;
    trans_tile(tile, w1, w1_t, ffg, 1024, 4096, id & 127, id >> 7);
  } else {                               // W2 (4096x1024)
    id -= 10240;
    trans_tile(tile, w2, w2_t, nullptr, 4096, 1024, id & 31, id >> 5);
  }
}

// rank-1 LN-bias rows: bql[3072] = b2@[Wq|Wkv], bkvx[2048] = b1@Wkv, bff1[4096] = fb@W1
__global__ void __launch_bounds__(256) bias_rows(
    const float* __restrict__ Wq, const float* __restrict__ Wkv,
    const float* __restrict__ W1, const float* __restrict__ b1,
    const float* __restrict__ b2, const float* __restrict__ fb,
    float* __restrict__ bql, float* __restrict__ bkvx, float* __restrict__ bff1) {
  int t = blockIdx.x * 256 + threadIdx.x;
  float acc = 0.f;
  if (t < 1024) {
    for (int k = 0; k < 1024; k++) acc += b2[k] * Wq[(size_t)k * 1024 + t];
    bql[t] = acc;
  } else if (t < 3072) {
    int n = t - 1024;
    for (int k = 0; k < 1024; k++) acc += b2[k] * Wkv[(size_t)k * 2048 + n];
    bql[t] = acc;
  } else if (t < 5120) {
    int n = t - 3072;
    for (int k = 0; k < 1024; k++) acc += b1[k] * Wkv[(size_t)k * 2048 + n];
    bkvx[n] = acc;
  } else {
    int n = t - 5120;
    for (int k = 0; k < 1024; k++) acc += fb[k] * W1[(size_t)k * 4096 + n];
    bff1[n] = acc;
  }
}

// ---------------- layernorm (cols = 1024) ----------------

__device__ __forceinline__ void ln_reduce(float s, float s2, int tid, float* red,
                                          float& mean, float& rstd) {
#pragma unroll
  for (int o = 32; o > 0; o >>= 1) {
    s += __shfl_down(s, o);
    s2 += __shfl_down(s2, o);
  }
  int w = tid >> 6;
  if ((tid & 63) == 0) { red[w] = s; red[4 + w] = s2; }
  __syncthreads();
  s = red[0] + red[1] + red[2] + red[3];
  s2 = red[4] + red[5] + red[6] + red[7];
  mean = s * (1.f / 1024.f);
  float var = s2 * (1.f / 1024.f) - mean * mean;
  rstd = rsqrtf(var + 1e-5f);
}

__global__ void __launch_bounds__(256) ln_to_bf16(const float* __restrict__ in,
                                                  const float* __restrict__ g,
                                                  const float* __restrict__ bb,
                                                  bf16* __restrict__ out) {
  __shared__ float red[8];
  int row = blockIdx.x, tid = threadIdx.x;
  const float* x = in + (size_t)row * 1024;
  float v[4], s = 0.f, s2 = 0.f;
#pragma unroll
  for (int j = 0; j < 4; j++) { v[j] = x[tid + j * 256]; s += v[j]; s2 += v[j] * v[j]; }
  float mean, rstd;
  ln_reduce(s, s2, tid, red, mean, rstd);
  bf16* o1 = out + (size_t)row * 1024;
#pragma unroll
  for (int j = 0; j < 4; j++) {
    int c = tid + j * 256;
    float y = (v[j] - mean) * rstd;
    if (g) y = y * g[c] + bb[c];
    o1[c] = __float2bfloat16(y);
  }
}

// fused: sum 4 split-K planes (+resid / +row-bias) -> sum_out (f32, optional),
// then pure/affine LN -> out (bf16 or f32)
enum { RL_RESID = 1, RL_BIAS = 2, RL_AFF = 4, RL_F32 = 8 };

template <int MODE>
__global__ void __launch_bounds__(256) red_ln(const float* __restrict__ parts, size_t plane,
                                              const float* __restrict__ resid,
                                              const float* __restrict__ rbias,
                                              float* __restrict__ sum_out,
                                              const float* __restrict__ g,
                                              const float* __restrict__ bb,
                                              void* __restrict__ out) {
  __shared__ float red[8];
  int row = blockIdx.x, tid = threadIdx.x;
  float v[4], s = 0.f, s2 = 0.f;
#pragma unroll
  for (int j = 0; j < 4; j++) {
    int c = tid + j * 256;
    size_t idx = (size_t)row * 1024 + c;
    float a = parts[idx] + parts[plane + idx] + parts[2 * plane + idx] + parts[3 * plane + idx];
    if (MODE & RL_RESID) a += resid[idx];
    if (MODE & RL_BIAS) a += rbias[c];
    if (sum_out) sum_out[idx] = a;
    v[j] = a; s += a; s2 += a * a;
  }
  float mean, rstd;
  ln_reduce(s, s2, tid, red, mean, rstd);
#pragma unroll
  for (int j = 0; j < 4; j++) {
    int c = tid + j * 256;
    size_t idx = (size_t)row * 1024 + c;
    float y = (v[j] - mean) * rstd;
    if (MODE & RL_AFF) y = y * g[c] + bb[c];
    if (MODE & RL_F32) ((float*)out)[idx] = y;
    else ((bf16*)out)[idx] = __float2bfloat16(y);
  }
}

// ---------------- GEMM: C(MxN) = A(MxK,bf16) @ Bt(NxK,bf16)^T ----------------
// 128x128 tile, BK=64 (half the barrier drains vs BK=32), global_load_lds w=16.
// grid.z = split-K; MODE=0 writes f32 partials at plane z*M*N.
// MB_DUAL: cols <1024 -> Cout (stride 1024), else -> Cout2 (stride 2048).

enum { MB_BIAS = 1, MB_RESID = 2, MB_GELU = 4, MB_BF16 = 8, MB_DUAL = 16 };

template <int MODE>
__global__ void __launch_bounds__(256, 2) gemm_bt(
    const bf16* __restrict__ A, const bf16* __restrict__ Bt,
    void* __restrict__ Cout, void* __restrict__ Cout2,
    const float* __restrict__ bias, const float* __restrict__ resid,
    int M, int N, int K) {
  __shared__ bf16 sA[128 * 64];
  __shared__ bf16 sB[128 * 64];
  int tid = threadIdx.x;
  int wave = tid >> 6, lane = tid & 63;
  int quad = lane >> 4, l16 = lane & 15;
  int wm = (wave >> 1) * 64, wn = (wave & 1) * 64;
  int m0 = blockIdx.y * 128, n0 = blockIdx.x * 128;
  int kPer = K / gridDim.z;
  int kBeg = blockIdx.z * kPer, kEnd = kBeg + kPer;

  // staging: chunk c covers rows c*32 + wave*8 .. +7; lane -> row += lane/8, col (lane&7)*8
  int lr = lane >> 3, lc = (lane & 7) * 8;
  const bf16* pA[4]; const bf16* pB[4]; bf16* dA[4]; bf16* dB[4];
#pragma unroll
  for (int c = 0; c < 4; c++) {
    int row = c * 32 + wave * 8 + lr;
    pA[c] = A + (size_t)min(m0 + row, M - 1) * K + lc;
    pB[c] = Bt + (size_t)(n0 + row) * K + lc;
    dA[c] = &sA[(c * 32 + wave * 8) * 64];
    dB[c] = &sB[(c * 32 + wave * 8) * 64];
  }

  f32x4 acc[4][4] = {};

  for (int k0 = kBeg; k0 < kEnd; k0 += 64) {
#pragma unroll
    for (int c = 0; c < 4; c++) gload16(pA[c] + k0, dA[c]);
#pragma unroll
    for (int c = 0; c < 4; c++) gload16(pB[c] + k0, dB[c]);
    __syncthreads();   // drains vmcnt: staged data visible
#pragma unroll
    for (int ks = 0; ks < 2; ks++) {
      short8 af[4], bfv[4];
#pragma unroll
      for (int i = 0; i < 4; i++)
        af[i] = *(const short8*)&sA[(wm + i * 16 + l16) * 64 + ks * 32 + quad * 8];
#pragma unroll
      for (int j = 0; j < 4; j++)
        bfv[j] = *(const short8*)&sB[(wn + j * 16 + l16) * 64 + ks * 32 + quad * 8];
#pragma unroll
      for (int i = 0; i < 4; i++)
#pragma unroll
        for (int j = 0; j < 4; j++)
          acc[i][j] = mfma16(af[i], bfv[j], acc[i][j]);
    }
    __syncthreads();   // frag reads done before next iter's stores
  }

  float* cf = (float*)Cout + (size_t)blockIdx.z * ((size_t)M * N);
#pragma unroll
  for (int i = 0; i < 4; i++) {
    int grb = m0 + wm + i * 16 + quad * 4;
#pragma unroll
    for (int j = 0; j < 4; j++) {
      int gc = n0 + wn + j * 16 + l16;
      float bv = (MODE & MB_BIAS) ? bias[gc] : 0.f;
#pragma unroll
      for (int r = 0; r < 4; r++) {
        int gr = grb + r;
        if (gr < M) {
          float vv = acc[i][j][r] + bv;
          if (MODE & MB_GELU) vv = 0.5f * vv * (1.f + erff(vv * 0.70710678118654752f));
          if (MODE & MB_RESID) vv += resid[(size_t)gr * N + gc];
          if (MODE & MB_DUAL) {
            if (gc < 1024) ((bf16*)Cout)[(size_t)gr * 1024 + gc] = __float2bfloat16(vv);
            else ((bf16*)Cout2)[(size_t)gr * 2048 + (gc - 1024)] = __float2bfloat16(vv);
          } else if (MODE & MB_BF16) {
            ((bf16*)Cout)[(size_t)gr * N + gc] = __float2bfloat16(vv);
          } else {
            cf[(size_t)gr * N + gc] = vv;
          }
        }
      }
    }
  }
}

// ---------------- fused attention: one block per (b,h) ----------------
// q: (b*64+m, h*64+d); K/V rows r<257 from kvx (b*257+r), 257<=r<321 from kvl
// (b*64+r-257); layout per row: [K: h*64+d | V: 1024+h*64+d]. Cols >=321 masked.

__global__ void __launch_bounds__(256, 2) attn(const bf16* __restrict__ qb,
                                               const bf16* __restrict__ kvx,
                                               const bf16* __restrict__ kvl,
                                               bf16* __restrict__ ob) {
  __shared__ bf16 sQ[64 * 64];
  __shared__ bf16 sKV[64 * 64];
  __shared__ bf16 sP[64 * 368];
  __shared__ float sRed[256];

  int h = blockIdx.x, b = blockIdx.y;
  int tid = threadIdx.x, wave = tid >> 6, lane = tid & 63;
  int quad = lane >> 4, l16 = lane & 15;

  const bf16* qg = qb + (size_t)b * 64 * 1024 + h * 64;
  auto kvrow = [&](int gr) -> const bf16* {
    return (gr < 257) ? kvx + ((size_t)(b * 257 + gr)) * 2048
                      : kvl + ((size_t)(b * 64 + (gr - 257))) * 2048;
  };

  {
    int r = tid >> 3, c = (tid & 7) * 8;
    *(uint4*)&sQ[r * 64 + c] = *(const uint4*)&qg[(size_t)r * 1024 + c];
    *(uint4*)&sQ[(r + 32) * 64 + c] = *(const uint4*)&qg[(size_t)(r + 32) * 1024 + c];
  }

  f32x4 accS[6][4] = {};   // wave owns score n-tile g*4+wave

  for (int g = 0; g < 6; g++) {
    __syncthreads();
    {
      int r = tid >> 3, c = (tid & 7) * 8;
      int gr = g * 64 + r;
      if (gr < 321) *(uint4*)&sKV[r * 64 + c] = *(const uint4*)(kvrow(gr) + h * 64 + c);
      gr += 32;
      if (gr < 321) *(uint4*)&sKV[(r + 32) * 64 + c] = *(const uint4*)(kvrow(gr) + h * 64 + c);
    }
    __syncthreads();
    if (g * 4 + wave < 21) {
#pragma unroll
      for (int ks = 0; ks < 2; ks++) {
        short8 bfr = *(const short8*)&sKV[(wave * 16 + l16) * 64 + ks * 32 + quad * 8];
#pragma unroll
        for (int i = 0; i < 4; i++) {
          short8 afr = *(const short8*)&sQ[(i * 16 + l16) * 64 + ks * 32 + quad * 8];
          accS[g][i] = mfma16(afr, bfr, accS[g][i]);
        }
      }
    }
  }

  // softmax over 321 valid cols
  float rmax[4][4], rsum[4][4];
#pragma unroll
  for (int i = 0; i < 4; i++)
#pragma unroll
    for (int r = 0; r < 4; r++) { rmax[i][r] = -1e30f; rsum[i][r] = 0.f; }

#pragma unroll
  for (int g = 0; g < 6; g++) {
    int col = (g * 4 + wave) * 16 + l16;
    bool valid = col < 321;
#pragma unroll
    for (int i = 0; i < 4; i++)
#pragma unroll
      for (int r = 0; r < 4; r++) {
        float v = accS[g][i][r] * 0.125f;
        accS[g][i][r] = v;
        if (valid) rmax[i][r] = fmaxf(rmax[i][r], v);
      }
  }
#pragma unroll
  for (int off = 1; off < 16; off <<= 1)
#pragma unroll
    for (int i = 0; i < 4; i++)
#pragma unroll
      for (int r = 0; r < 4; r++)
        rmax[i][r] = fmaxf(rmax[i][r], __shfl_xor(rmax[i][r], off));
  if (l16 == 0) {
#pragma unroll
    for (int i = 0; i < 4; i++)
#pragma unroll
      for (int r = 0; r < 4; r++)
        sRed[wave * 64 + i * 16 + quad * 4 + r] = rmax[i][r];
  }
  __syncthreads();
#pragma unroll
  for (int i = 0; i < 4; i++)
#pragma unroll
    for (int r = 0; r < 4; r++) {
      int row = i * 16 + quad * 4 + r;
      rmax[i][r] = fmaxf(fmaxf(sRed[row], sRed[64 + row]),
                         fmaxf(sRed[128 + row], sRed[192 + row]));
    }
  __syncthreads();

#pragma unroll
  for (int g = 0; g < 6; g++) {
    int col = (g * 4 + wave) * 16 + l16;
    bool valid = col < 321;
#pragma unroll
    for (int i = 0; i < 4; i++)
#pragma unroll
      for (int r = 0; r < 4; r++) {
        float pv = valid ? __expf(accS[g][i][r] - rmax[i][r]) : 0.f;
        rsum[i][r] += pv;
        if (col < 352) sP[(i * 16 + quad * 4 + r) * 368 + col] = __float2bfloat16(pv);
      }
  }
#pragma unroll
  for (int off = 1; off < 16; off <<= 1)
#pragma unroll
    for (int i = 0; i < 4; i++)
#pragma unroll
      for (int r = 0; r < 4; r++)
        rsum[i][r] += __shfl_xor(rsum[i][r], off);
  if (l16 == 0) {
#pragma unroll
    for (int i = 0; i < 4; i++)
#pragma unroll
      for (int r = 0; r < 4; r++)
        sRed[wave * 64 + i * 16 + quad * 4 + r] = rsum[i][r];
  }
  __syncthreads();
#pragma unroll
  for (int i = 0; i < 4; i++)
#pragma unroll
    for (int r = 0; r < 4; r++) {
      int row = i * 16 + quad * 4 + r;
      rsum[i][r] = sRed[row] + sRed[64 + row] + sRed[128 + row] + sRed[192 + row];
    }

  // O = P @ V
  f32x4 accO[4] = {};
  const short* sKVs = (const short*)sKV;
  for (int cch = 0; cch < 6; cch++) {
    __syncthreads();
    {
      int r = tid >> 3, c = (tid & 7) * 8;
      int gr = cch * 64 + r;
      if (gr < 321) *(uint4*)&sKV[r * 64 + c] = *(const uint4*)(kvrow(gr) + 1024 + h * 64 + c);
      gr += 32;
      if (gr < 321) *(uint4*)&sKV[(r + 32) * 64 + c] = *(const uint4*)(kvrow(gr) + 1024 + h * 64 + c);
    }
    __syncthreads();
    int nks = (cch == 5) ? 1 : 2;   // P zero past col 336
    for (int ks = 0; ks < nks; ks++) {
      short8 bv;
#pragma unroll
      for (int jj = 0; jj < 8; jj++)
        bv[jj] = sKVs[(ks * 32 + quad * 8 + jj) * 64 + wave * 16 + l16];
#pragma unroll
      for (int i = 0; i < 4; i++) {
        short8 ap = *(const short8*)&sP[(i * 16 + l16) * 368 + cch * 64 + ks * 32 + quad * 8];
        accO[i] = mfma16(ap, bv, accO[i]);
      }
    }
  }

#pragma unroll
  for (int i = 0; i < 4; i++)
#pragma unroll
    for (int r = 0; r < 4; r++) {
      int row = i * 16 + quad * 4 + r;
      ob[(size_t)(b * 64 + row) * 1024 + h * 64 + wave * 16 + l16] =
          __float2bfloat16(accO[i][r] / rsum[i][r]);
    }
}

// ---------------- host orchestration ----------------

extern "C" void kernel_launch(void* const* d_in, const int* in_sizes, int n_in,
                              void* d_out, int out_size, void* d_ws, size_t ws_size,
                              hipStream_t stream) {
  (void)in_sizes; (void)n_in; (void)out_size; (void)ws_size;
  const float* x    = (const float*)d_in[0];
  const float* lin  = (const float*)d_in[1];
  const float* piw  = (const float*)d_in[2];
  const float* pib  = (const float*)d_in[3];
  const float* ln1g = (const float*)d_in[4];
  const float* ln1b = (const float*)d_in[5];
  const float* ln2g = (const float*)d_in[6];
  const float* ln2b = (const float*)d_in[7];
  const float* Wq   = (const float*)d_in[8];
  const float* Wkv  = (const float*)d_in[9];
  const float* Wo   = (const float*)d_in[10];
  const float* ffg  = (const float*)d_in[11];
  const float* ffb  = (const float*)d_in[12];
  const float* W1   = (const float*)d_in[13];
  const float* W2   = (const float*)d_in[14];
  const float* poW  = (const float*)d_in[15];
  const float* pob  = (const float*)d_in[16];
  const float* nog  = (const float*)d_in[17];
  const float* nob  = (const float*)d_in[18];

  char* p = (char*)d_ws;
  auto alloc = [&](size_t bytes) -> char* {
    char* q = p; p += (bytes + 255) & ~(size_t)255; return q;
  };
  bf16* pin_t   = (bf16*)alloc((size_t)1024 * 768 * 2);
  bf16* pout_t  = (bf16*)alloc((size_t)1024 * 1024 * 2);
  bf16* wql_t   = (bf16*)alloc((size_t)3072 * 1024 * 2);
  bf16* wkvx_t  = (bf16*)alloc((size_t)2048 * 1024 * 2);
  bf16* wo_t    = (bf16*)alloc((size_t)1024 * 1024 * 2);
  bf16* w1_t    = (bf16*)alloc((size_t)4096 * 1024 * 2);
  bf16* w2_t    = (bf16*)alloc((size_t)1024 * 4096 * 2);
  float* bql    = (float*)alloc(3072 * 4);
  float* bkvx   = (float*)alloc(2048 * 4);
  float* bff1   = (float*)alloc(4096 * 4);
  bf16* x_bf    = (bf16*)alloc((size_t)8224 * 768 * 2);
  float* xf     = (float*)alloc((size_t)8224 * 1024 * 4);   // proj_in out / split-K planes
  bf16* xhat    = (bf16*)alloc((size_t)8224 * 1024 * 2);
  bf16* lathat  = (bf16*)alloc((size_t)2048 * 1024 * 2);
  bf16* qbuf    = (bf16*)alloc((size_t)2048 * 1024 * 2);
  bf16* kvx     = (bf16*)alloc((size_t)8224 * 2048 * 2);
  bf16* kvl     = (bf16*)alloc((size_t)2048 * 2048 * 2);
  bf16* obuf    = (bf16*)alloc((size_t)2048 * 1024 * 2);
  float* lat    = (float*)alloc((size_t)2048 * 1024 * 4);
  float* lat2   = (float*)alloc((size_t)2048 * 1024 * 4);
  bf16* lnffhat = (bf16*)alloc((size_t)2048 * 1024 * 2);
  bf16* h1      = (bf16*)alloc((size_t)2048 * 4096 * 2);

  const size_t MN = (size_t)2048 * 1024;   // split-K plane

  // prologue
  cvt_f32_bf16<<<6316032 / 256, 256, 0, stream>>>(x, x_bf, 6316032);
  transpose_cvt<<<dim3(32, 24), 256, 0, stream>>>(piw, pin_t, 768, 1024);
  transpose_cvt<<<dim3(32, 32), 256, 0, stream>>>(poW, pout_t, 1024, 1024);
  bcast_latents<<<8192, 256, 0, stream>>>(lin, lat);
  ln_to_bf16<<<2048, 256, 0, stream>>>(lat, nullptr, nullptr, lathat);
  gemm_bt<MB_BIAS><<<dim3(8, 65), 256, 0, stream>>>(x_bf, pin_t, xf, nullptr, pib, nullptr,
                                                    8224, 1024, 768);
  ln_to_bf16<<<8224, 256, 0, stream>>>(xf, nullptr, nullptr, xhat);

  for (int i = 0; i < 8; i++) {
    transpose_all<<<14336, 256, 0, stream>>>(
        Wq + (size_t)i * 1048576, Wkv + (size_t)i * 2097152, Wo + (size_t)i * 1048576,
        W1 + (size_t)i * 4194304, W2 + (size_t)i * 4194304,
        ln1g + i * 1024, ln2g + i * 1024, ffg + i * 1024,
        wql_t, wkvx_t, wo_t, w1_t, w2_t);
    bias_rows<<<36, 256, 0, stream>>>(Wq + (size_t)i * 1048576, Wkv + (size_t)i * 2097152,
                                      W1 + (size_t)i * 4194304, ln1b + i * 1024,
                                      ln2b + i * 1024, ffb + i * 1024, bql, bkvx, bff1);
    // kv_x = xhat @ (g1*Wkv) + b1@Wkv
    gemm_bt<MB_BIAS | MB_BF16><<<dim3(16, 65), 256, 0, stream>>>(
        xhat, wkvx_t, kvx, nullptr, bkvx, nullptr, 8224, 2048, 1024);
    // [q | kv_l] = lathat @ (g2*[Wq|Wkv]) + b2@[Wq|Wkv]
    gemm_bt<MB_BIAS | MB_BF16 | MB_DUAL><<<dim3(24, 16), 256, 0, stream>>>(
        lathat, wql_t, qbuf, kvl, bql, nullptr, 2048, 3072, 1024);
    attn<<<dim3(16, 32), 256, 0, stream>>>(qbuf, kvx, kvl, obuf);
    // lat2 = o @ Wo + lat ; lnffhat = LN(lat2)
    gemm_bt<0><<<dim3(8, 16, 4), 256, 0, stream>>>(obuf, wo_t, xf, nullptr, nullptr, nullptr,
                                                   2048, 1024, 1024);
    red_ln<RL_RESID><<<2048, 256, 0, stream>>>(xf, MN, lat, nullptr, lat2,
                                               nullptr, nullptr, lnffhat);
    // h1 = gelu(lnffhat @ (ffg*W1) + ffb@W1)
    gemm_bt<MB_BIAS | MB_GELU | MB_BF16><<<dim3(32, 16), 256, 0, stream>>>(
        lnffhat, w1_t, h1, nullptr, bff1, nullptr, 2048, 4096, 1024);
    // lat = h1 @ W2 + lat2 ; lathat = LN(lat)
    gemm_bt<0><<<dim3(8, 16, 4), 256, 0, stream>>>(h1, w2_t, xf, nullptr, nullptr, nullptr,
                                                   2048, 1024, 4096);
    red_ln<RL_RESID><<<2048, 256, 0, stream>>>(xf, MN, lat2, nullptr, lat,
                                               nullptr, nullptr, lathat);
  }

  // epilogue: out = LN(lat @ proj_out_w + pob) * nog + nob
  cvt_f32_bf16<<<2097152 / 256, 256, 0, stream>>>(lat, lnffhat, 2097152);
  gemm_bt<0><<<dim3(8, 16, 4), 256, 0, stream>>>(lnffhat, pout_t, xf, nullptr, nullptr, nullptr,
                                                 2048, 1024, 1024);
  red_ln<RL_BIAS | RL_AFF | RL_F32><<<2048, 256, 0, stream>>>(
      xf, MN, nullptr, pob, nullptr, nog, nob, (float*)d_out);
}